// Round 1
// baseline (237.949 us; speedup 1.0000x reference)
//
#include <hip/hip_runtime.h>
#include <math.h>

// Burgers PINN: u = MLP(x,t), outputs u, u_x, u_t (via f), u_xx at 1M points
// + plain forward at 3x16384 IC/boundary points.
// Forward-mode AD with 4 channels: (val, d/dx, d/dt, d2/dx2).

#define NU_CONST 0.0031830988618379067f  // 0.01 / pi

__device__ __forceinline__ float fast_tanh(float x) {
    float ax = fabsf(x);
    float e  = __expf(-2.0f * ax);                  // e in (0,1]
    float r  = __fdividef(1.0f - e, 1.0f + e);      // tanh(|x|)
    return copysignf(r, x);
}

// One hidden 10->10 tanh layer, propagating 4 forward-mode channels.
__device__ __forceinline__ void hidden10_ad(const float* __restrict__ W,
                                            const float* __restrict__ B,
                                            float h[10], float hx[10],
                                            float ht[10], float hxx[10]) {
    float z[10], zx[10], zt[10], zxx[10];
#pragma unroll
    for (int j = 0; j < 10; ++j) {
        z[j] = B[j]; zx[j] = 0.f; zt[j] = 0.f; zxx[j] = 0.f;
    }
#pragma unroll
    for (int i = 0; i < 10; ++i) {
#pragma unroll
        for (int j = 0; j < 10; ++j) {
            float w = W[i * 10 + j];          // uniform -> s_load, SGPR operand
            z[j]   = fmaf(h[i],   w, z[j]);
            zx[j]  = fmaf(hx[i],  w, zx[j]);
            zt[j]  = fmaf(ht[i],  w, zt[j]);
            zxx[j] = fmaf(hxx[i], w, zxx[j]);
        }
    }
#pragma unroll
    for (int j = 0; j < 10; ++j) {
        float v = fast_tanh(z[j]);
        float s = 1.0f - v * v;
        h[j]   = v;
        hx[j]  = s * zx[j];
        ht[j]  = s * zt[j];
        // d2/dx2 tanh(z) = s*zxx - 2*v*s*zx^2
        hxx[j] = fmaf(s, zxx[j], -2.0f * v * s * zx[j] * zx[j]);
    }
}

// Values-only hidden layer for the forward-only points.
__device__ __forceinline__ void hidden10_fwd(const float* __restrict__ W,
                                             const float* __restrict__ B,
                                             float h[10]) {
    float z[10];
#pragma unroll
    for (int j = 0; j < 10; ++j) z[j] = B[j];
#pragma unroll
    for (int i = 0; i < 10; ++i) {
#pragma unroll
        for (int j = 0; j < 10; ++j)
            z[j] = fmaf(h[i], W[i * 10 + j], z[j]);
    }
#pragma unroll
    for (int j = 0; j < 10; ++j) h[j] = fast_tanh(z[j]);
}

__global__ __launch_bounds__(256) void pinn_colloc_kernel(
    const float* __restrict__ Xf,
    const float* __restrict__ W1, const float* __restrict__ b1,
    const float* __restrict__ W2, const float* __restrict__ b2,
    const float* __restrict__ W3, const float* __restrict__ b3,
    const float* __restrict__ W4, const float* __restrict__ b4,
    const float* __restrict__ W5, const float* __restrict__ b5,
    const float* __restrict__ W6, const float* __restrict__ b6,
    const float* __restrict__ W7, const float* __restrict__ b7,
    const float* __restrict__ W8, const float* __restrict__ b8,
    const float* __restrict__ W9, const float* __restrict__ b9,
    float* __restrict__ out_u, float* __restrict__ out_f,
    float* __restrict__ out_ux, float* __restrict__ out_uxx, int n) {
    int idx = blockIdx.x * blockDim.x + threadIdx.x;
    if (idx >= n) return;
    float x = Xf[2 * idx];
    float t = Xf[2 * idx + 1];

    float h[10], hx[10], ht[10], hxx[10];
    // Layer 1: 2 -> 10, tanh. Seeds: dx=(1,0), dt=(0,1), dxx=0.
#pragma unroll
    for (int j = 0; j < 10; ++j) {
        float wx = W1[j];        // W1[0][j]
        float wt = W1[10 + j];   // W1[1][j]
        float z  = fmaf(x, wx, fmaf(t, wt, b1[j]));
        float v  = fast_tanh(z);
        float s  = 1.0f - v * v;
        h[j]   = v;
        hx[j]  = s * wx;
        ht[j]  = s * wt;
        hxx[j] = -2.0f * v * s * wx * wx;   // zxx = 0 at layer 1
    }

    hidden10_ad(W2, b2, h, hx, ht, hxx);
    hidden10_ad(W3, b3, h, hx, ht, hxx);
    hidden10_ad(W4, b4, h, hx, ht, hxx);
    hidden10_ad(W5, b5, h, hx, ht, hxx);
    hidden10_ad(W6, b6, h, hx, ht, hxx);
    hidden10_ad(W7, b7, h, hx, ht, hxx);
    hidden10_ad(W8, b8, h, hx, ht, hxx);

    // Layer 9: 10 -> 1, linear.
    float u = b9[0], ux = 0.f, ut = 0.f, uxx = 0.f;
#pragma unroll
    for (int i = 0; i < 10; ++i) {
        float w = W9[i];
        u   = fmaf(h[i],   w, u);
        ux  = fmaf(hx[i],  w, ux);
        ut  = fmaf(ht[i],  w, ut);
        uxx = fmaf(hxx[i], w, uxx);
    }

    out_u[idx]   = u;
    out_ux[idx]  = ux;
    out_uxx[idx] = uxx;
    out_f[idx]   = fmaf(u, ux, ut) - NU_CONST * uxx;  // u_t + u*u_x - nu*u_xx
}

__global__ __launch_bounds__(256) void pinn_fwd_kernel(
    const float* __restrict__ X0, const float* __restrict__ XL,
    const float* __restrict__ XR,
    const float* __restrict__ W1, const float* __restrict__ b1,
    const float* __restrict__ W2, const float* __restrict__ b2,
    const float* __restrict__ W3, const float* __restrict__ b3,
    const float* __restrict__ W4, const float* __restrict__ b4,
    const float* __restrict__ W5, const float* __restrict__ b5,
    const float* __restrict__ W6, const float* __restrict__ b6,
    const float* __restrict__ W7, const float* __restrict__ b7,
    const float* __restrict__ W8, const float* __restrict__ b8,
    const float* __restrict__ W9, const float* __restrict__ b9,
    float* __restrict__ O0, float* __restrict__ OL, float* __restrict__ OR_,
    int n) {
    int idx = blockIdx.x * blockDim.x + threadIdx.x;
    if (idx >= 3 * n) return;
    const float* X;
    float* O;
    int k;
    if (idx < n)            { X = X0; O = O0;  k = idx; }
    else if (idx < 2 * n)   { X = XL; O = OL;  k = idx - n; }
    else                    { X = XR; O = OR_; k = idx - 2 * n; }

    float x = X[2 * k];
    float t = X[2 * k + 1];

    float h[10];
#pragma unroll
    for (int j = 0; j < 10; ++j) {
        float z = fmaf(x, W1[j], fmaf(t, W1[10 + j], b1[j]));
        h[j] = fast_tanh(z);
    }
    hidden10_fwd(W2, b2, h);
    hidden10_fwd(W3, b3, h);
    hidden10_fwd(W4, b4, h);
    hidden10_fwd(W5, b5, h);
    hidden10_fwd(W6, b6, h);
    hidden10_fwd(W7, b7, h);
    hidden10_fwd(W8, b8, h);

    float u = b9[0];
#pragma unroll
    for (int i = 0; i < 10; ++i) u = fmaf(h[i], W9[i], u);
    O[k] = u;
}

extern "C" void kernel_launch(void* const* d_in, const int* in_sizes, int n_in,
                              void* d_out, int out_size, void* d_ws, size_t ws_size,
                              hipStream_t stream) {
    const float* Xf = (const float*)d_in[0];
    const float* X0 = (const float*)d_in[1];
    const float* XL = (const float*)d_in[2];
    const float* XR = (const float*)d_in[3];
    const float* W[9];
    const float* B[9];
    for (int i = 0; i < 9; ++i) {
        W[i] = (const float*)d_in[4 + 2 * i];
        B[i] = (const float*)d_in[5 + 2 * i];
    }
    int NF = in_sizes[0] / 2;
    int N0 = in_sizes[1] / 2;
    int NB = in_sizes[2] / 2;

    float* out = (float*)d_out;
    float* out_u   = out;                         // u_pred_f      [NF]
    float* out_0   = out + NF;                    // u_pred_0      [N0]
    float* out_bl  = out + NF + N0;               // u_pred_b_left [NB]
    float* out_br  = out + NF + N0 + NB;          // u_pred_b_right[NB]
    float* out_f   = out + NF + N0 + 2 * NB;      // f             [NF]
    float* out_ux  = out_f + NF;                  // u_x           [NF]
    float* out_uxx = out_ux + NF;                 // u_xx          [NF]

    dim3 blk(256);
    dim3 grd((NF + 255) / 256);
    pinn_colloc_kernel<<<grd, blk, 0, stream>>>(
        Xf, W[0], B[0], W[1], B[1], W[2], B[2], W[3], B[3], W[4], B[4],
        W[5], B[5], W[6], B[6], W[7], B[7], W[8], B[8],
        out_u, out_f, out_ux, out_uxx, NF);

    int total_fwd = 3 * N0;  // N0 == NB == 16384
    dim3 grd2((total_fwd + 255) / 256);
    pinn_fwd_kernel<<<grd2, blk, 0, stream>>>(
        X0, XL, XR, W[0], B[0], W[1], B[1], W[2], B[2], W[3], B[3], W[4], B[4],
        W[5], B[5], W[6], B[6], W[7], B[7], W[8], B[8],
        out_0, out_bl, out_br, N0);
}

// Round 2
// 218.994 us; speedup vs baseline: 1.0866x; 1.0866x over previous
//
#include <hip/hip_runtime.h>
#include <math.h>

// Burgers PINN: u = MLP(x,t) (2->10x7->1, tanh), outputs u, f, u_x, u_xx at 1M
// collocation points + plain forward at 3x16384 IC/boundary points.
// Forward-mode AD with 4 channels: (val, d/dx, d/dt, d2/dx2).
//
// R1: __launch_bounds__(256,4) -> VGPR cap 128 (R0's default alloc was 40 VGPR
// -> massive AGPR spill traffic on an 80-float working set); 5-op tanh.

#define NU_CONST 0.0031830988618379067f  // 0.01 / pi

// tanh(x) = 1 - 2/(exp(2x)+1): v_mul, v_exp, v_add, v_rcp, v_fma = 5 ops.
// x->+inf: exp=inf, rcp=0, result 1.  x->-inf: exp=0, rcp=1, result -1.
__device__ __forceinline__ float fast_tanh(float x) {
    float e = __expf(2.0f * x);
    float r = __builtin_amdgcn_rcpf(e + 1.0f);
    return fmaf(-2.0f, r, 1.0f);
}

// One hidden 10->10 tanh layer, propagating 4 forward-mode channels.
__device__ __forceinline__ void hidden10_ad(const float* __restrict__ W,
                                            const float* __restrict__ B,
                                            float h[10], float hx[10],
                                            float ht[10], float hxx[10]) {
    float z[10], zx[10], zt[10], zxx[10];
#pragma unroll
    for (int j = 0; j < 10; ++j) {
        z[j] = B[j]; zx[j] = 0.f; zt[j] = 0.f; zxx[j] = 0.f;
    }
#pragma unroll
    for (int i = 0; i < 10; ++i) {
#pragma unroll
        for (int j = 0; j < 10; ++j) {
            float w = W[i * 10 + j];          // uniform -> s_load, SGPR operand
            z[j]   = fmaf(h[i],   w, z[j]);
            zx[j]  = fmaf(hx[i],  w, zx[j]);
            zt[j]  = fmaf(ht[i],  w, zt[j]);
            zxx[j] = fmaf(hxx[i], w, zxx[j]);
        }
    }
#pragma unroll
    for (int j = 0; j < 10; ++j) {
        float v = fast_tanh(z[j]);
        float s = fmaf(-v, v, 1.0f);          // 1 - v^2
        float sx = s * zx[j];                 // new hx
        // d2/dx2 tanh(z) = s*zxx - 2*v*s*zx^2 = s*zxx + (-2v)*(sx*zx)
        float m2v = -2.0f * v;
        h[j]   = v;
        hx[j]  = sx;
        ht[j]  = s * zt[j];
        hxx[j] = fmaf(s, zxx[j], m2v * (sx * zx[j]));
    }
}

// Values-only hidden layer for the forward-only points.
__device__ __forceinline__ void hidden10_fwd(const float* __restrict__ W,
                                             const float* __restrict__ B,
                                             float h[10]) {
    float z[10];
#pragma unroll
    for (int j = 0; j < 10; ++j) z[j] = B[j];
#pragma unroll
    for (int i = 0; i < 10; ++i) {
#pragma unroll
        for (int j = 0; j < 10; ++j)
            z[j] = fmaf(h[i], W[i * 10 + j], z[j]);
    }
#pragma unroll
    for (int j = 0; j < 10; ++j) h[j] = fast_tanh(z[j]);
}

__global__ __launch_bounds__(256, 4) void pinn_colloc_kernel(
    const float* __restrict__ Xf,
    const float* __restrict__ W1, const float* __restrict__ b1,
    const float* __restrict__ W2, const float* __restrict__ b2,
    const float* __restrict__ W3, const float* __restrict__ b3,
    const float* __restrict__ W4, const float* __restrict__ b4,
    const float* __restrict__ W5, const float* __restrict__ b5,
    const float* __restrict__ W6, const float* __restrict__ b6,
    const float* __restrict__ W7, const float* __restrict__ b7,
    const float* __restrict__ W8, const float* __restrict__ b8,
    const float* __restrict__ W9, const float* __restrict__ b9,
    float* __restrict__ out_u, float* __restrict__ out_f,
    float* __restrict__ out_ux, float* __restrict__ out_uxx, int n) {
    int idx = blockIdx.x * blockDim.x + threadIdx.x;
    if (idx >= n) return;
    float x = Xf[2 * idx];
    float t = Xf[2 * idx + 1];

    float h[10], hx[10], ht[10], hxx[10];
    // Layer 1: 2 -> 10, tanh. Seeds: dx=(1,0), dt=(0,1), dxx=0.
#pragma unroll
    for (int j = 0; j < 10; ++j) {
        float wx = W1[j];        // W1[0][j]
        float wt = W1[10 + j];   // W1[1][j]
        float z  = fmaf(x, wx, fmaf(t, wt, b1[j]));
        float v  = fast_tanh(z);
        float s  = fmaf(-v, v, 1.0f);
        float sx = s * wx;
        h[j]   = v;
        hx[j]  = sx;
        ht[j]  = s * wt;
        hxx[j] = -2.0f * v * (sx * wx);   // zxx = 0 at layer 1
    }

    hidden10_ad(W2, b2, h, hx, ht, hxx);
    hidden10_ad(W3, b3, h, hx, ht, hxx);
    hidden10_ad(W4, b4, h, hx, ht, hxx);
    hidden10_ad(W5, b5, h, hx, ht, hxx);
    hidden10_ad(W6, b6, h, hx, ht, hxx);
    hidden10_ad(W7, b7, h, hx, ht, hxx);
    hidden10_ad(W8, b8, h, hx, ht, hxx);

    // Layer 9: 10 -> 1, linear.
    float u = b9[0], ux = 0.f, ut = 0.f, uxx = 0.f;
#pragma unroll
    for (int i = 0; i < 10; ++i) {
        float w = W9[i];
        u   = fmaf(h[i],   w, u);
        ux  = fmaf(hx[i],  w, ux);
        ut  = fmaf(ht[i],  w, ut);
        uxx = fmaf(hxx[i], w, uxx);
    }

    out_u[idx]   = u;
    out_ux[idx]  = ux;
    out_uxx[idx] = uxx;
    out_f[idx]   = fmaf(u, ux, ut) - NU_CONST * uxx;  // u_t + u*u_x - nu*u_xx
}

__global__ __launch_bounds__(256, 4) void pinn_fwd_kernel(
    const float* __restrict__ X0, const float* __restrict__ XL,
    const float* __restrict__ XR,
    const float* __restrict__ W1, const float* __restrict__ b1,
    const float* __restrict__ W2, const float* __restrict__ b2,
    const float* __restrict__ W3, const float* __restrict__ b3,
    const float* __restrict__ W4, const float* __restrict__ b4,
    const float* __restrict__ W5, const float* __restrict__ b5,
    const float* __restrict__ W6, const float* __restrict__ b6,
    const float* __restrict__ W7, const float* __restrict__ b7,
    const float* __restrict__ W8, const float* __restrict__ b8,
    const float* __restrict__ W9, const float* __restrict__ b9,
    float* __restrict__ O0, float* __restrict__ OL, float* __restrict__ OR_,
    int n) {
    int idx = blockIdx.x * blockDim.x + threadIdx.x;
    if (idx >= 3 * n) return;
    const float* X;
    float* O;
    int k;
    if (idx < n)            { X = X0; O = O0;  k = idx; }
    else if (idx < 2 * n)   { X = XL; O = OL;  k = idx - n; }
    else                    { X = XR; O = OR_; k = idx - 2 * n; }

    float x = X[2 * k];
    float t = X[2 * k + 1];

    float h[10];
#pragma unroll
    for (int j = 0; j < 10; ++j) {
        float z = fmaf(x, W1[j], fmaf(t, W1[10 + j], b1[j]));
        h[j] = fast_tanh(z);
    }
    hidden10_fwd(W2, b2, h);
    hidden10_fwd(W3, b3, h);
    hidden10_fwd(W4, b4, h);
    hidden10_fwd(W5, b5, h);
    hidden10_fwd(W6, b6, h);
    hidden10_fwd(W7, b7, h);
    hidden10_fwd(W8, b8, h);

    float u = b9[0];
#pragma unroll
    for (int i = 0; i < 10; ++i) u = fmaf(h[i], W9[i], u);
    O[k] = u;
}

extern "C" void kernel_launch(void* const* d_in, const int* in_sizes, int n_in,
                              void* d_out, int out_size, void* d_ws, size_t ws_size,
                              hipStream_t stream) {
    const float* Xf = (const float*)d_in[0];
    const float* X0 = (const float*)d_in[1];
    const float* XL = (const float*)d_in[2];
    const float* XR = (const float*)d_in[3];
    const float* W[9];
    const float* B[9];
    for (int i = 0; i < 9; ++i) {
        W[i] = (const float*)d_in[4 + 2 * i];
        B[i] = (const float*)d_in[5 + 2 * i];
    }
    int NF = in_sizes[0] / 2;
    int N0 = in_sizes[1] / 2;
    int NB = in_sizes[2] / 2;

    float* out = (float*)d_out;
    float* out_u   = out;                         // u_pred_f      [NF]
    float* out_0   = out + NF;                    // u_pred_0      [N0]
    float* out_bl  = out + NF + N0;               // u_pred_b_left [NB]
    float* out_br  = out + NF + N0 + NB;          // u_pred_b_right[NB]
    float* out_f   = out + NF + N0 + 2 * NB;      // f             [NF]
    float* out_ux  = out_f + NF;                  // u_x           [NF]
    float* out_uxx = out_ux + NF;                 // u_xx          [NF]

    dim3 blk(256);
    dim3 grd((NF + 255) / 256);
    pinn_colloc_kernel<<<grd, blk, 0, stream>>>(
        Xf, W[0], B[0], W[1], B[1], W[2], B[2], W[3], B[3], W[4], B[4],
        W[5], B[5], W[6], B[6], W[7], B[7], W[8], B[8],
        out_u, out_f, out_ux, out_uxx, NF);

    int total_fwd = 3 * N0;  // N0 == NB == 16384
    dim3 grd2((total_fwd + 255) / 256);
    pinn_fwd_kernel<<<grd2, blk, 0, stream>>>(
        X0, XL, XR, W[0], B[0], W[1], B[1], W[2], B[2], W[3], B[3], W[4], B[4],
        W[5], B[5], W[6], B[6], W[7], B[7], W[8], B[8],
        out_0, out_bl, out_br, N0);
}

// Round 3
// 218.919 us; speedup vs baseline: 1.0869x; 1.0003x over previous
//
#include <hip/hip_runtime.h>
#include <math.h>

// Burgers PINN: u = MLP(x,t) (2->10x7->1, tanh), outputs u, f, u_x, u_xx at 1M
// collocation points + plain forward at 3x16384 IC/boundary points.
// Forward-mode AD with 4 channels: (val, d/dx, d/dt, d2/dx2).
//
// R2: hardware-guaranteed tanh via __builtin_amdgcn_exp2f (bypass libm expf
// lowering risk), peeled i=0 accumulator init (kill v_movs),
// __launch_bounds__(256,3) for register headroom, float2 input load.

#define NU_CONST 0.0031830988618379067f   // 0.01 / pi
#define TWO_OVER_LN2 2.8853900817779268f  // 2 / ln(2)

// tanh(x) = 1 - 2/(exp2(x*2/ln2)+1): v_mul, v_exp, v_add, v_rcp, v_fma.
// x->+inf: exp2=inf, rcp=0 -> 1.  x->-inf: exp2=0, rcp=1 -> -1.
__device__ __forceinline__ float fast_tanh(float x) {
    float e = __builtin_amdgcn_exp2f(x * TWO_OVER_LN2);
    float r = __builtin_amdgcn_rcpf(e + 1.0f);
    return fmaf(-2.0f, r, 1.0f);
}

// One hidden 10->10 tanh layer, propagating 4 forward-mode channels.
__device__ __forceinline__ void hidden10_ad(const float* __restrict__ W,
                                            const float* __restrict__ B,
                                            float h[10], float hx[10],
                                            float ht[10], float hxx[10]) {
    float z[10], zx[10], zt[10], zxx[10];
    // Peeled i=0: init accumulators directly (no v_mov zero-init pass).
#pragma unroll
    for (int j = 0; j < 10; ++j) {
        float w = W[j];                   // W[0][j], uniform -> SGPR operand
        z[j]   = fmaf(h[0], w, B[j]);
        zx[j]  = hx[0]  * w;
        zt[j]  = ht[0]  * w;
        zxx[j] = hxx[0] * w;
    }
#pragma unroll
    for (int i = 1; i < 10; ++i) {
#pragma unroll
        for (int j = 0; j < 10; ++j) {
            float w = W[i * 10 + j];
            z[j]   = fmaf(h[i],   w, z[j]);
            zx[j]  = fmaf(hx[i],  w, zx[j]);
            zt[j]  = fmaf(ht[i],  w, zt[j]);
            zxx[j] = fmaf(hxx[i], w, zxx[j]);
        }
    }
#pragma unroll
    for (int j = 0; j < 10; ++j) {
        float v = fast_tanh(z[j]);
        float s = fmaf(-v, v, 1.0f);      // 1 - v^2
        float sx = s * zx[j];             // new hx
        float m2v = -2.0f * v;
        h[j]   = v;
        hx[j]  = sx;
        ht[j]  = s * zt[j];
        // d2/dx2 tanh(z) = s*zxx - 2*v*s*zx^2 = s*zxx + (-2v)*(sx*zx)
        hxx[j] = fmaf(s, zxx[j], m2v * (sx * zx[j]));
    }
}

// Values-only hidden layer for the forward-only points.
__device__ __forceinline__ void hidden10_fwd(const float* __restrict__ W,
                                             const float* __restrict__ B,
                                             float h[10]) {
    float z[10];
#pragma unroll
    for (int j = 0; j < 10; ++j) z[j] = fmaf(h[0], W[j], B[j]);
#pragma unroll
    for (int i = 1; i < 10; ++i) {
#pragma unroll
        for (int j = 0; j < 10; ++j)
            z[j] = fmaf(h[i], W[i * 10 + j], z[j]);
    }
#pragma unroll
    for (int j = 0; j < 10; ++j) h[j] = fast_tanh(z[j]);
}

__global__ __launch_bounds__(256, 3) void pinn_colloc_kernel(
    const float* __restrict__ Xf,
    const float* __restrict__ W1, const float* __restrict__ b1,
    const float* __restrict__ W2, const float* __restrict__ b2,
    const float* __restrict__ W3, const float* __restrict__ b3,
    const float* __restrict__ W4, const float* __restrict__ b4,
    const float* __restrict__ W5, const float* __restrict__ b5,
    const float* __restrict__ W6, const float* __restrict__ b6,
    const float* __restrict__ W7, const float* __restrict__ b7,
    const float* __restrict__ W8, const float* __restrict__ b8,
    const float* __restrict__ W9, const float* __restrict__ b9,
    float* __restrict__ out_u, float* __restrict__ out_f,
    float* __restrict__ out_ux, float* __restrict__ out_uxx, int n) {
    int idx = blockIdx.x * blockDim.x + threadIdx.x;
    if (idx >= n) return;
    float2 xt = ((const float2*)Xf)[idx];
    float x = xt.x;
    float t = xt.y;

    float h[10], hx[10], ht[10], hxx[10];
    // Layer 1: 2 -> 10, tanh. Seeds: dx=(1,0), dt=(0,1), dxx=0.
#pragma unroll
    for (int j = 0; j < 10; ++j) {
        float wx = W1[j];        // W1[0][j]
        float wt = W1[10 + j];   // W1[1][j]
        float z  = fmaf(x, wx, fmaf(t, wt, b1[j]));
        float v  = fast_tanh(z);
        float s  = fmaf(-v, v, 1.0f);
        float sx = s * wx;
        h[j]   = v;
        hx[j]  = sx;
        ht[j]  = s * wt;
        hxx[j] = -2.0f * v * (sx * wx);   // zxx = 0 at layer 1
    }

    hidden10_ad(W2, b2, h, hx, ht, hxx);
    hidden10_ad(W3, b3, h, hx, ht, hxx);
    hidden10_ad(W4, b4, h, hx, ht, hxx);
    hidden10_ad(W5, b5, h, hx, ht, hxx);
    hidden10_ad(W6, b6, h, hx, ht, hxx);
    hidden10_ad(W7, b7, h, hx, ht, hxx);
    hidden10_ad(W8, b8, h, hx, ht, hxx);

    // Layer 9: 10 -> 1, linear.
    float u = b9[0], ux = 0.f, ut = 0.f, uxx = 0.f;
#pragma unroll
    for (int i = 0; i < 10; ++i) {
        float w = W9[i];
        u   = fmaf(h[i],   w, u);
        ux  = fmaf(hx[i],  w, ux);
        ut  = fmaf(ht[i],  w, ut);
        uxx = fmaf(hxx[i], w, uxx);
    }

    out_u[idx]   = u;
    out_ux[idx]  = ux;
    out_uxx[idx] = uxx;
    out_f[idx]   = fmaf(u, ux, ut) - NU_CONST * uxx;  // u_t + u*u_x - nu*u_xx
}

__global__ __launch_bounds__(256, 3) void pinn_fwd_kernel(
    const float* __restrict__ X0, const float* __restrict__ XL,
    const float* __restrict__ XR,
    const float* __restrict__ W1, const float* __restrict__ b1,
    const float* __restrict__ W2, const float* __restrict__ b2,
    const float* __restrict__ W3, const float* __restrict__ b3,
    const float* __restrict__ W4, const float* __restrict__ b4,
    const float* __restrict__ W5, const float* __restrict__ b5,
    const float* __restrict__ W6, const float* __restrict__ b6,
    const float* __restrict__ W7, const float* __restrict__ b7,
    const float* __restrict__ W8, const float* __restrict__ b8,
    const float* __restrict__ W9, const float* __restrict__ b9,
    float* __restrict__ O0, float* __restrict__ OL, float* __restrict__ OR_,
    int n) {
    int idx = blockIdx.x * blockDim.x + threadIdx.x;
    if (idx >= 3 * n) return;
    const float* X;
    float* O;
    int k;
    if (idx < n)            { X = X0; O = O0;  k = idx; }
    else if (idx < 2 * n)   { X = XL; O = OL;  k = idx - n; }
    else                    { X = XR; O = OR_; k = idx - 2 * n; }

    float2 xt = ((const float2*)X)[k];
    float x = xt.x;
    float t = xt.y;

    float h[10];
#pragma unroll
    for (int j = 0; j < 10; ++j) {
        float z = fmaf(x, W1[j], fmaf(t, W1[10 + j], b1[j]));
        h[j] = fast_tanh(z);
    }
    hidden10_fwd(W2, b2, h);
    hidden10_fwd(W3, b3, h);
    hidden10_fwd(W4, b4, h);
    hidden10_fwd(W5, b5, h);
    hidden10_fwd(W6, b6, h);
    hidden10_fwd(W7, b7, h);
    hidden10_fwd(W8, b8, h);

    float u = b9[0];
#pragma unroll
    for (int i = 0; i < 10; ++i) u = fmaf(h[i], W9[i], u);
    O[k] = u;
}

extern "C" void kernel_launch(void* const* d_in, const int* in_sizes, int n_in,
                              void* d_out, int out_size, void* d_ws, size_t ws_size,
                              hipStream_t stream) {
    const float* Xf = (const float*)d_in[0];
    const float* X0 = (const float*)d_in[1];
    const float* XL = (const float*)d_in[2];
    const float* XR = (const float*)d_in[3];
    const float* W[9];
    const float* B[9];
    for (int i = 0; i < 9; ++i) {
        W[i] = (const float*)d_in[4 + 2 * i];
        B[i] = (const float*)d_in[5 + 2 * i];
    }
    int NF = in_sizes[0] / 2;
    int N0 = in_sizes[1] / 2;
    int NB = in_sizes[2] / 2;

    float* out = (float*)d_out;
    float* out_u   = out;                         // u_pred_f      [NF]
    float* out_0   = out + NF;                    // u_pred_0      [N0]
    float* out_bl  = out + NF + N0;               // u_pred_b_left [NB]
    float* out_br  = out + NF + N0 + NB;          // u_pred_b_right[NB]
    float* out_f   = out + NF + N0 + 2 * NB;      // f             [NF]
    float* out_ux  = out_f + NF;                  // u_x           [NF]
    float* out_uxx = out_ux + NF;                 // u_xx          [NF]

    dim3 blk(256);
    dim3 grd((NF + 255) / 256);
    pinn_colloc_kernel<<<grd, blk, 0, stream>>>(
        Xf, W[0], B[0], W[1], B[1], W[2], B[2], W[3], B[3], W[4], B[4],
        W[5], B[5], W[6], B[6], W[7], B[7], W[8], B[8],
        out_u, out_f, out_ux, out_uxx, NF);

    int total_fwd = 3 * N0;  // N0 == NB == 16384
    dim3 grd2((total_fwd + 255) / 256);
    pinn_fwd_kernel<<<grd2, blk, 0, stream>>>(
        X0, XL, XR, W[0], B[0], W[1], B[1], W[2], B[2], W[3], B[3], W[4], B[4],
        W[5], B[5], W[6], B[6], W[7], B[7], W[8], B[8],
        out_0, out_bl, out_br, N0);
}

// Round 5
// 174.187 us; speedup vs baseline: 1.3661x; 1.2568x over previous
//
#include <hip/hip_runtime.h>
#include <math.h>

// Burgers PINN: u = MLP(x,t) (2->10x7->1, tanh), outputs u, f, u_x, u_xx at 1M
// collocation points + plain forward at 3x16384 IC/boundary points.
// Forward-mode AD with 4 channels: (val, d/dx, d/dt, d2/dx2).
//
// R4: R3 (packed fp32 v_pk_fma_f32 over output-neuron pairs) with the macro
// compile error fixed — pk_fma is a real inline function, constants are
// named v2f values (no compound literals inside macro args).

#define NU_CONST 0.0031830988618379067f   // 0.01 / pi
#define TWO_OVER_LN2 2.8853900817779268f  // 2 / ln(2)

typedef float v2f __attribute__((ext_vector_type(2)));

__device__ __forceinline__ v2f pk_fma(v2f a, v2f b, v2f c) {
    return __builtin_elementwise_fma(a, b, c);
}

__device__ __forceinline__ v2f splat2(float s) {
    v2f r;
    r.x = s;
    r.y = s;
    return r;
}

__device__ __forceinline__ float fast_tanh(float x) {
    float e = __builtin_amdgcn_exp2f(x * TWO_OVER_LN2);
    float r = __builtin_amdgcn_rcpf(e + 1.0f);
    return fmaf(-2.0f, r, 1.0f);
}

// Packed tanh: v = tanh(z) elementwise on a pair.
__device__ __forceinline__ v2f tanh2(v2f z2) {
    v2f a2 = z2 * splat2(TWO_OVER_LN2);
    v2f e2;
    e2.x = __builtin_amdgcn_exp2f(a2.x);
    e2.y = __builtin_amdgcn_exp2f(a2.y);
    v2f ep = e2 + splat2(1.0f);
    v2f r2;
    r2.x = __builtin_amdgcn_rcpf(ep.x);
    r2.y = __builtin_amdgcn_rcpf(ep.y);
    return pk_fma(splat2(-2.0f), r2, splat2(1.0f));
}

// One hidden 10->10 tanh layer, 4 forward-mode channels, packed over j-pairs.
__device__ __forceinline__ void hidden10_ad(const float* __restrict__ W,
                                            const float* __restrict__ B,
                                            float h[10], float hx[10],
                                            float ht[10], float hxx[10]) {
    v2f Z[5], Zx[5], Zt[5], Zxx[5];
    // Peeled i=0: init accumulators directly.
    {
        v2f hs   = splat2(h[0]);
        v2f hxs  = splat2(hx[0]);
        v2f hts  = splat2(ht[0]);
        v2f hxxs = splat2(hxx[0]);
#pragma unroll
        for (int jp = 0; jp < 5; ++jp) {
            v2f w2 = *(const v2f*)(W + 2 * jp);   // row 0, uniform -> s_load
            v2f b2 = *(const v2f*)(B + 2 * jp);
            Z[jp]   = pk_fma(hs, w2, b2);
            Zx[jp]  = hxs * w2;
            Zt[jp]  = hts * w2;
            Zxx[jp] = hxxs * w2;
        }
    }
#pragma unroll
    for (int i = 1; i < 10; ++i) {
        v2f hs   = splat2(h[i]);
        v2f hxs  = splat2(hx[i]);
        v2f hts  = splat2(ht[i]);
        v2f hxxs = splat2(hxx[i]);
#pragma unroll
        for (int jp = 0; jp < 5; ++jp) {
            v2f w2 = *(const v2f*)(W + i * 10 + 2 * jp);
            Z[jp]   = pk_fma(hs,   w2, Z[jp]);
            Zx[jp]  = pk_fma(hxs,  w2, Zx[jp]);
            Zt[jp]  = pk_fma(hts,  w2, Zt[jp]);
            Zxx[jp] = pk_fma(hxxs, w2, Zxx[jp]);
        }
    }
#pragma unroll
    for (int jp = 0; jp < 5; ++jp) {
        v2f v2v = tanh2(Z[jp]);
        v2f s2  = pk_fma(-v2v, v2v, splat2(1.0f));   // 1 - v^2
        v2f sx2 = s2 * Zx[jp];                       // new hx
        v2f m2v = splat2(-2.0f) * v2v;
        v2f htn2 = s2 * Zt[jp];
        // d2/dx2 tanh(z) = s*zxx - 2*v*s*zx^2 = s*zxx + (-2v)*(sx*zx)
        v2f hxxn2 = pk_fma(s2, Zxx[jp], m2v * (sx2 * Zx[jp]));
        h[2*jp]   = v2v.x;   h[2*jp+1]   = v2v.y;
        hx[2*jp]  = sx2.x;   hx[2*jp+1]  = sx2.y;
        ht[2*jp]  = htn2.x;  ht[2*jp+1]  = htn2.y;
        hxx[2*jp] = hxxn2.x; hxx[2*jp+1] = hxxn2.y;
    }
}

// Values-only hidden layer, packed over j-pairs.
__device__ __forceinline__ void hidden10_fwd(const float* __restrict__ W,
                                             const float* __restrict__ B,
                                             float h[10]) {
    v2f Z[5];
    {
        v2f hs = splat2(h[0]);
#pragma unroll
        for (int jp = 0; jp < 5; ++jp) {
            v2f w2 = *(const v2f*)(W + 2 * jp);
            v2f b2 = *(const v2f*)(B + 2 * jp);
            Z[jp] = pk_fma(hs, w2, b2);
        }
    }
#pragma unroll
    for (int i = 1; i < 10; ++i) {
        v2f hs = splat2(h[i]);
#pragma unroll
        for (int jp = 0; jp < 5; ++jp) {
            v2f w2 = *(const v2f*)(W + i * 10 + 2 * jp);
            Z[jp] = pk_fma(hs, w2, Z[jp]);
        }
    }
#pragma unroll
    for (int jp = 0; jp < 5; ++jp) {
        v2f v2v = tanh2(Z[jp]);
        h[2*jp] = v2v.x;
        h[2*jp+1] = v2v.y;
    }
}

__global__ __launch_bounds__(256)
__attribute__((amdgpu_waves_per_eu(3, 4)))
void pinn_colloc_kernel(
    const float* __restrict__ Xf,
    const float* __restrict__ W1, const float* __restrict__ b1,
    const float* __restrict__ W2, const float* __restrict__ b2,
    const float* __restrict__ W3, const float* __restrict__ b3,
    const float* __restrict__ W4, const float* __restrict__ b4,
    const float* __restrict__ W5, const float* __restrict__ b5,
    const float* __restrict__ W6, const float* __restrict__ b6,
    const float* __restrict__ W7, const float* __restrict__ b7,
    const float* __restrict__ W8, const float* __restrict__ b8,
    const float* __restrict__ W9, const float* __restrict__ b9,
    float* __restrict__ out_u, float* __restrict__ out_f,
    float* __restrict__ out_ux, float* __restrict__ out_uxx, int n) {
    int idx = blockIdx.x * blockDim.x + threadIdx.x;
    if (idx >= n) return;
    float2 xt = ((const float2*)Xf)[idx];
    float x = xt.x;
    float t = xt.y;

    float h[10], hx[10], ht[10], hxx[10];
    // Layer 1: 2 -> 10, tanh. Seeds: dx=(1,0), dt=(0,1), dxx=0.
    {
        v2f xs = splat2(x);
        v2f ts = splat2(t);
#pragma unroll
        for (int jp = 0; jp < 5; ++jp) {
            v2f wx2 = *(const v2f*)(W1 + 2 * jp);        // W1 row 0
            v2f wt2 = *(const v2f*)(W1 + 10 + 2 * jp);   // W1 row 1
            v2f b2  = *(const v2f*)(b1 + 2 * jp);
            v2f z2  = pk_fma(xs, wx2, pk_fma(ts, wt2, b2));
            v2f v2v = tanh2(z2);
            v2f s2  = pk_fma(-v2v, v2v, splat2(1.0f));
            v2f sx2 = s2 * wx2;
            v2f m2v = splat2(-2.0f) * v2v;
            v2f st2 = s2 * wt2;
            v2f sxx2 = m2v * (sx2 * wx2);   // zxx = 0 at layer 1
            h[2*jp]   = v2v.x;  h[2*jp+1]   = v2v.y;
            hx[2*jp]  = sx2.x;  hx[2*jp+1]  = sx2.y;
            ht[2*jp]  = st2.x;  ht[2*jp+1]  = st2.y;
            hxx[2*jp] = sxx2.x; hxx[2*jp+1] = sxx2.y;
        }
    }

    hidden10_ad(W2, b2, h, hx, ht, hxx);
    hidden10_ad(W3, b3, h, hx, ht, hxx);
    hidden10_ad(W4, b4, h, hx, ht, hxx);
    hidden10_ad(W5, b5, h, hx, ht, hxx);
    hidden10_ad(W6, b6, h, hx, ht, hxx);
    hidden10_ad(W7, b7, h, hx, ht, hxx);
    hidden10_ad(W8, b8, h, hx, ht, hxx);

    // Layer 9: 10 -> 1, linear. Scalar epilogue (once per point).
    float u = b9[0], ux = 0.f, ut = 0.f, uxx = 0.f;
#pragma unroll
    for (int i = 0; i < 10; ++i) {
        float w = W9[i];
        u   = fmaf(h[i],   w, u);
        ux  = fmaf(hx[i],  w, ux);
        ut  = fmaf(ht[i],  w, ut);
        uxx = fmaf(hxx[i], w, uxx);
    }

    out_u[idx]   = u;
    out_ux[idx]  = ux;
    out_uxx[idx] = uxx;
    out_f[idx]   = fmaf(u, ux, ut) - NU_CONST * uxx;  // u_t + u*u_x - nu*u_xx
}

__global__ __launch_bounds__(256)
__attribute__((amdgpu_waves_per_eu(3, 4)))
void pinn_fwd_kernel(
    const float* __restrict__ X0, const float* __restrict__ XL,
    const float* __restrict__ XR,
    const float* __restrict__ W1, const float* __restrict__ b1,
    const float* __restrict__ W2, const float* __restrict__ b2,
    const float* __restrict__ W3, const float* __restrict__ b3,
    const float* __restrict__ W4, const float* __restrict__ b4,
    const float* __restrict__ W5, const float* __restrict__ b5,
    const float* __restrict__ W6, const float* __restrict__ b6,
    const float* __restrict__ W7, const float* __restrict__ b7,
    const float* __restrict__ W8, const float* __restrict__ b8,
    const float* __restrict__ W9, const float* __restrict__ b9,
    float* __restrict__ O0, float* __restrict__ OL, float* __restrict__ OR_,
    int n) {
    int idx = blockIdx.x * blockDim.x + threadIdx.x;
    if (idx >= 3 * n) return;
    const float* X;
    float* O;
    int k;
    if (idx < n)            { X = X0; O = O0;  k = idx; }
    else if (idx < 2 * n)   { X = XL; O = OL;  k = idx - n; }
    else                    { X = XR; O = OR_; k = idx - 2 * n; }

    float2 xt = ((const float2*)X)[k];
    float x = xt.x;
    float t = xt.y;

    float h[10];
#pragma unroll
    for (int j = 0; j < 10; ++j) {
        float z = fmaf(x, W1[j], fmaf(t, W1[10 + j], b1[j]));
        h[j] = fast_tanh(z);
    }
    hidden10_fwd(W2, b2, h);
    hidden10_fwd(W3, b3, h);
    hidden10_fwd(W4, b4, h);
    hidden10_fwd(W5, b5, h);
    hidden10_fwd(W6, b6, h);
    hidden10_fwd(W7, b7, h);
    hidden10_fwd(W8, b8, h);

    float u = b9[0];
#pragma unroll
    for (int i = 0; i < 10; ++i) u = fmaf(h[i], W9[i], u);
    O[k] = u;
}

extern "C" void kernel_launch(void* const* d_in, const int* in_sizes, int n_in,
                              void* d_out, int out_size, void* d_ws, size_t ws_size,
                              hipStream_t stream) {
    const float* Xf = (const float*)d_in[0];
    const float* X0 = (const float*)d_in[1];
    const float* XL = (const float*)d_in[2];
    const float* XR = (const float*)d_in[3];
    const float* W[9];
    const float* B[9];
    for (int i = 0; i < 9; ++i) {
        W[i] = (const float*)d_in[4 + 2 * i];
        B[i] = (const float*)d_in[5 + 2 * i];
    }
    int NF = in_sizes[0] / 2;
    int N0 = in_sizes[1] / 2;
    int NB = in_sizes[2] / 2;

    float* out = (float*)d_out;
    float* out_u   = out;                         // u_pred_f      [NF]
    float* out_0   = out + NF;                    // u_pred_0      [N0]
    float* out_bl  = out + NF + N0;               // u_pred_b_left [NB]
    float* out_br  = out + NF + N0 + NB;          // u_pred_b_right[NB]
    float* out_f   = out + NF + N0 + 2 * NB;      // f             [NF]
    float* out_ux  = out_f + NF;                  // u_x           [NF]
    float* out_uxx = out_ux + NF;                 // u_xx          [NF]

    dim3 blk(256);
    dim3 grd((NF + 255) / 256);
    pinn_colloc_kernel<<<grd, blk, 0, stream>>>(
        Xf, W[0], B[0], W[1], B[1], W[2], B[2], W[3], B[3], W[4], B[4],
        W[5], B[5], W[6], B[6], W[7], B[7], W[8], B[8],
        out_u, out_f, out_ux, out_uxx, NF);

    int total_fwd = 3 * N0;  // N0 == NB == 16384
    dim3 grd2((total_fwd + 255) / 256);
    pinn_fwd_kernel<<<grd2, blk, 0, stream>>>(
        X0, XL, XR, W[0], B[0], W[1], B[1], W[2], B[2], W[3], B[3], W[4], B[4],
        W[5], B[5], W[6], B[6], W[7], B[7], W[8], B[8],
        out_0, out_bl, out_br, N0);
}

// Round 6
// 170.176 us; speedup vs baseline: 1.3982x; 1.0236x over previous
//
#include <hip/hip_runtime.h>
#include <math.h>

// Burgers PINN: u = MLP(x,t) (2->10x7->1, tanh), outputs u, f, u_x, u_xx at 1M
// collocation points + plain forward at 3x16384 IC/boundary points.
// Forward-mode AD with 4 channels: (val, d/dx, d/dt, d2/dx2).
//
// R6: inline-asm v_pk_fma_f32 with op_sel broadcast of the activation half —
// kills splat v_movs and keeps all state packed in v2f pairs end-to-end
// (also pins state to arch VGPRs: asm "v" constraints can't be AGPRs).
// Both kernels merged into one launch (fwd = 192 trailing blocks).

#define NU_CONST 0.0031830988618379067f   // 0.01 / pi
#define TWO_OVER_LN2 2.8853900817779268f  // 2 / ln(2)

typedef float v2f __attribute__((ext_vector_type(2)));

__device__ __forceinline__ v2f splat2(float s) {
    v2f r; r.x = s; r.y = s; return r;
}
__device__ __forceinline__ v2f pk_fma(v2f a, v2f b, v2f c) {
    return __builtin_elementwise_fma(a, b, c);
}

// acc(pair) += act.lo * w(pair): op_sel broadcasts src0's LOW half to both
// result halves (op_sel[0]=0 for lo result, op_sel_hi[0]=0 for hi result).
__device__ __forceinline__ void fma_blo(v2f& acc, v2f act, v2f w) {
    asm("v_pk_fma_f32 %0, %1, %2, %0 op_sel:[0,0,0] op_sel_hi:[0,1,1]"
        : "+v"(acc) : "v"(act), "s"(w));
}
// acc(pair) += act.hi * w(pair)
__device__ __forceinline__ void fma_bhi(v2f& acc, v2f act, v2f w) {
    asm("v_pk_fma_f32 %0, %1, %2, %0 op_sel:[1,0,0] op_sel_hi:[1,1,1]"
        : "+v"(acc) : "v"(act), "s"(w));
}
// dst(pair) = act.lo * w(pair)  (peel of row 0 for derivative channels)
__device__ __forceinline__ v2f mul_blo(v2f act, v2f w) {
    v2f d;
    asm("v_pk_mul_f32 %0, %1, %2 op_sel:[0,0] op_sel_hi:[0,1]"
        : "=v"(d) : "v"(act), "s"(w));
    return d;
}

__device__ __forceinline__ float fast_tanh(float x) {
    float e = __builtin_amdgcn_exp2f(x * TWO_OVER_LN2);
    float r = __builtin_amdgcn_rcpf(e + 1.0f);
    return fmaf(-2.0f, r, 1.0f);
}

// Packed tanh on a pair.
__device__ __forceinline__ v2f tanh2(v2f z2) {
    v2f a2 = z2 * splat2(TWO_OVER_LN2);
    v2f e2;
    e2.x = __builtin_amdgcn_exp2f(a2.x);
    e2.y = __builtin_amdgcn_exp2f(a2.y);
    v2f ep = e2 + splat2(1.0f);
    v2f r2;
    r2.x = __builtin_amdgcn_rcpf(ep.x);
    r2.y = __builtin_amdgcn_rcpf(ep.y);
    return pk_fma(splat2(-2.0f), r2, splat2(1.0f));
}

// One hidden 10->10 tanh layer, 4 AD channels, fully packed state.
// H/Hx/Ht/Hxx are v2f[5]: element i lives in H[i/2] half (i&1).
__device__ __forceinline__ void hidden10_ad_pk(const float* __restrict__ W,
                                               const float* __restrict__ B,
                                               v2f H[5], v2f Hx[5],
                                               v2f Ht[5], v2f Hxx[5]) {
    v2f Z[5], Zx[5], Zt[5], Zxx[5];
    // Row 0 peel: Z = bias + h0*w; derivative channels = act0 * w.
#pragma unroll
    for (int jp = 0; jp < 5; ++jp) {
        v2f w2 = *(const v2f*)(W + 2 * jp);   // row 0, uniform -> s_load
        v2f b2 = *(const v2f*)(B + 2 * jp);
        Z[jp] = b2;                            // SGPR->VGPR pair copy
        fma_blo(Z[jp], H[0], w2);
        Zx[jp]  = mul_blo(Hx[0],  w2);
        Zt[jp]  = mul_blo(Ht[0],  w2);
        Zxx[jp] = mul_blo(Hxx[0], w2);
    }
#pragma unroll
    for (int i = 1; i < 10; ++i) {
        const int p = i >> 1;
#pragma unroll
        for (int jp = 0; jp < 5; ++jp) {
            v2f w2 = *(const v2f*)(W + i * 10 + 2 * jp);
            if (i & 1) {
                fma_bhi(Z[jp],   H[p],   w2);
                fma_bhi(Zx[jp],  Hx[p],  w2);
                fma_bhi(Zt[jp],  Ht[p],  w2);
                fma_bhi(Zxx[jp], Hxx[p], w2);
            } else {
                fma_blo(Z[jp],   H[p],   w2);
                fma_blo(Zx[jp],  Hx[p],  w2);
                fma_blo(Zt[jp],  Ht[p],  w2);
                fma_blo(Zxx[jp], Hxx[p], w2);
            }
        }
    }
#pragma unroll
    for (int jp = 0; jp < 5; ++jp) {
        v2f v2v = tanh2(Z[jp]);
        v2f s2  = pk_fma(-v2v, v2v, splat2(1.0f));   // 1 - v^2
        v2f sx2 = s2 * Zx[jp];
        v2f m2v = splat2(-2.0f) * v2v;
        H[jp]   = v2v;
        Hx[jp]  = sx2;
        Ht[jp]  = s2 * Zt[jp];
        // d2/dx2 tanh(z) = s*zxx + (-2v)*(sx*zx)
        Hxx[jp] = pk_fma(s2, Zxx[jp], m2v * (sx2 * Zx[jp]));
    }
}

// Values-only hidden layer (boundary/IC points), packed over j-pairs.
__device__ __forceinline__ void hidden10_fwd(const float* __restrict__ W,
                                             const float* __restrict__ B,
                                             float h[10]) {
    v2f Z[5];
    {
        v2f hs = splat2(h[0]);
#pragma unroll
        for (int jp = 0; jp < 5; ++jp) {
            v2f w2 = *(const v2f*)(W + 2 * jp);
            v2f b2 = *(const v2f*)(B + 2 * jp);
            Z[jp] = pk_fma(hs, w2, b2);
        }
    }
#pragma unroll
    for (int i = 1; i < 10; ++i) {
        v2f hs = splat2(h[i]);
#pragma unroll
        for (int jp = 0; jp < 5; ++jp) {
            v2f w2 = *(const v2f*)(W + i * 10 + 2 * jp);
            Z[jp] = pk_fma(hs, w2, Z[jp]);
        }
    }
#pragma unroll
    for (int jp = 0; jp < 5; ++jp) {
        v2f v2v = tanh2(Z[jp]);
        h[2*jp] = v2v.x;
        h[2*jp+1] = v2v.y;
    }
}

__global__ __launch_bounds__(256)
__attribute__((amdgpu_waves_per_eu(3, 4)))
void pinn_fused_kernel(
    const float* __restrict__ Xf,
    const float* __restrict__ X0, const float* __restrict__ XL,
    const float* __restrict__ XR,
    const float* __restrict__ W1, const float* __restrict__ b1,
    const float* __restrict__ W2, const float* __restrict__ b2,
    const float* __restrict__ W3, const float* __restrict__ b3,
    const float* __restrict__ W4, const float* __restrict__ b4,
    const float* __restrict__ W5, const float* __restrict__ b5,
    const float* __restrict__ W6, const float* __restrict__ b6,
    const float* __restrict__ W7, const float* __restrict__ b7,
    const float* __restrict__ W8, const float* __restrict__ b8,
    const float* __restrict__ W9, const float* __restrict__ b9,
    float* __restrict__ out_u, float* __restrict__ out_f,
    float* __restrict__ out_ux, float* __restrict__ out_uxx,
    float* __restrict__ O0, float* __restrict__ OL, float* __restrict__ OR_,
    int n_colloc_blocks, int NF, int N0) {
    if ((int)blockIdx.x < n_colloc_blocks) {
        // ---------------- collocation path: 4 AD channels ----------------
        int idx = blockIdx.x * blockDim.x + threadIdx.x;
        if (idx >= NF) return;
        float2 xt = ((const float2*)Xf)[idx];
        float x = xt.x;
        float t = xt.y;

        v2f H[5], Hx[5], Ht[5], Hxx[5];
        // Layer 1: 2 -> 10, tanh. Seeds: dx=(1,0), dt=(0,1), dxx=0.
        {
            v2f xs = splat2(x);
            v2f ts = splat2(t);
#pragma unroll
            for (int jp = 0; jp < 5; ++jp) {
                v2f wx2 = *(const v2f*)(W1 + 2 * jp);        // W1 row 0
                v2f wt2 = *(const v2f*)(W1 + 10 + 2 * jp);   // W1 row 1
                v2f b2  = *(const v2f*)(b1 + 2 * jp);
                v2f z2  = pk_fma(xs, wx2, pk_fma(ts, wt2, b2));
                v2f v2v = tanh2(z2);
                v2f s2  = pk_fma(-v2v, v2v, splat2(1.0f));
                v2f sx2 = s2 * wx2;
                v2f m2v = splat2(-2.0f) * v2v;
                H[jp]   = v2v;
                Hx[jp]  = sx2;
                Ht[jp]  = s2 * wt2;
                Hxx[jp] = m2v * (sx2 * wx2);   // zxx = 0 at layer 1
            }
        }

        hidden10_ad_pk(W2, b2, H, Hx, Ht, Hxx);
        hidden10_ad_pk(W3, b3, H, Hx, Ht, Hxx);
        hidden10_ad_pk(W4, b4, H, Hx, Ht, Hxx);
        hidden10_ad_pk(W5, b5, H, Hx, Ht, Hxx);
        hidden10_ad_pk(W6, b6, H, Hx, Ht, Hxx);
        hidden10_ad_pk(W7, b7, H, Hx, Ht, Hxx);
        hidden10_ad_pk(W8, b8, H, Hx, Ht, Hxx);

        // Layer 9: 10 -> 1, linear. Pairwise dot then horizontal add.
        v2f u2, ux2, ut2, uxx2;
        {
            v2f w2 = *(const v2f*)(W9);
            u2   = H[0]   * w2;
            ux2  = Hx[0]  * w2;
            ut2  = Ht[0]  * w2;
            uxx2 = Hxx[0] * w2;
        }
#pragma unroll
        for (int jp = 1; jp < 5; ++jp) {
            v2f w2 = *(const v2f*)(W9 + 2 * jp);
            u2   = pk_fma(H[jp],   w2, u2);
            ux2  = pk_fma(Hx[jp],  w2, ux2);
            ut2  = pk_fma(Ht[jp],  w2, ut2);
            uxx2 = pk_fma(Hxx[jp], w2, uxx2);
        }
        float u   = b9[0] + (u2.x + u2.y);
        float ux  = ux2.x + ux2.y;
        float ut  = ut2.x + ut2.y;
        float uxx = uxx2.x + uxx2.y;

        out_u[idx]   = u;
        out_ux[idx]  = ux;
        out_uxx[idx] = uxx;
        out_f[idx]   = fmaf(u, ux, ut) - NU_CONST * uxx;  // u_t + u*u_x - nu*u_xx
    } else {
        // ---------------- forward-only path: IC + boundaries ----------------
        int idx = (blockIdx.x - n_colloc_blocks) * blockDim.x + threadIdx.x;
        if (idx >= 3 * N0) return;
        const float* X;
        float* O;
        int k;
        if (idx < N0)            { X = X0; O = O0;  k = idx; }
        else if (idx < 2 * N0)   { X = XL; O = OL;  k = idx - N0; }
        else                     { X = XR; O = OR_; k = idx - 2 * N0; }

        float2 xt = ((const float2*)X)[k];
        float x = xt.x;
        float t = xt.y;

        float h[10];
#pragma unroll
        for (int j = 0; j < 10; ++j) {
            float z = fmaf(x, W1[j], fmaf(t, W1[10 + j], b1[j]));
            h[j] = fast_tanh(z);
        }
        hidden10_fwd(W2, b2, h);
        hidden10_fwd(W3, b3, h);
        hidden10_fwd(W4, b4, h);
        hidden10_fwd(W5, b5, h);
        hidden10_fwd(W6, b6, h);
        hidden10_fwd(W7, b7, h);
        hidden10_fwd(W8, b8, h);

        float u = b9[0];
#pragma unroll
        for (int i = 0; i < 10; ++i) u = fmaf(h[i], W9[i], u);
        O[k] = u;
    }
}

extern "C" void kernel_launch(void* const* d_in, const int* in_sizes, int n_in,
                              void* d_out, int out_size, void* d_ws, size_t ws_size,
                              hipStream_t stream) {
    const float* Xf = (const float*)d_in[0];
    const float* X0 = (const float*)d_in[1];
    const float* XL = (const float*)d_in[2];
    const float* XR = (const float*)d_in[3];
    const float* W[9];
    const float* B[9];
    for (int i = 0; i < 9; ++i) {
        W[i] = (const float*)d_in[4 + 2 * i];
        B[i] = (const float*)d_in[5 + 2 * i];
    }
    int NF = in_sizes[0] / 2;
    int N0 = in_sizes[1] / 2;
    int NB = in_sizes[2] / 2;

    float* out = (float*)d_out;
    float* out_u   = out;                         // u_pred_f      [NF]
    float* out_0   = out + NF;                    // u_pred_0      [N0]
    float* out_bl  = out + NF + N0;               // u_pred_b_left [NB]
    float* out_br  = out + NF + N0 + NB;          // u_pred_b_right[NB]
    float* out_f   = out + NF + N0 + 2 * NB;      // f             [NF]
    float* out_ux  = out_f + NF;                  // u_x           [NF]
    float* out_uxx = out_ux + NF;                 // u_xx          [NF]

    int n_colloc_blocks = (NF + 255) / 256;
    int n_fwd_blocks    = (3 * N0 + 255) / 256;
    dim3 blk(256);
    dim3 grd(n_colloc_blocks + n_fwd_blocks);
    pinn_fused_kernel<<<grd, blk, 0, stream>>>(
        Xf, X0, XL, XR,
        W[0], B[0], W[1], B[1], W[2], B[2], W[3], B[3], W[4], B[4],
        W[5], B[5], W[6], B[6], W[7], B[7], W[8], B[8],
        out_u, out_f, out_ux, out_uxx,
        out_0, out_bl, out_br,
        n_colloc_blocks, NF, N0);
}